// Round 18
// baseline (421.565 us; speedup 1.0000x reference)
//
#include <hip/hip_runtime.h>
#include <hip/hip_bf16.h>
#include <math.h>

typedef __bf16 bf16x8 __attribute__((ext_vector_type(8)));
typedef float f32x4 __attribute__((ext_vector_type(4)));

#define DEVI __device__ __forceinline__

// async global->LDS, 16B per lane. LDS dest must be wave-uniform-base + lane*16.
DEVI void gload_lds16(const __bf16* g, __bf16* l) {
    __builtin_amdgcn_global_load_lds(
        (const __attribute__((address_space(1))) void*)g,
        (__attribute__((address_space(3))) void*)l, 16, 0, 0);
}

// branchless erf, Abramowitz-Stegun 7.1.26 (round-14 verified: -12us on MLP1)
DEVI float erf_fast(float y) {
    const float ay = fabsf(y);
    const float t = __builtin_amdgcn_rcpf(fmaf(0.3275911f, ay, 1.0f));
    float p = 1.061405429f;
    p = fmaf(p, t, -1.453152027f);
    p = fmaf(p, t, 1.421413741f);
    p = fmaf(p, t, -0.284496736f);
    p = fmaf(p, t, 0.254829592f);
    p = p * t;
    const float e = exp2f(-y * y * 1.4426950408889634f);
    return copysignf(1.0f - p * e, y);
}

// ---------------------------------------------------------------------------
// dtype sniffer (2-byte fallback path only). flag[0]=1 -> fp32 storage.
__global__ void sniff_kernel(const unsigned short* __restrict__ x, int* flags) {
    const int tid = threadIdx.x;  // 256
    const unsigned short u = x[tid * 2];
    const int e = (u >> 7) & 0xFF;
    const int zero = (u == 0) ? 1 : 0;
    const int sane = ((e >= 0x71 && e <= 0x8E) || ((u & 0x7FFF) == 0)) ? 1 : 0;
    const unsigned long long mz = __ballot(zero != 0);
    const unsigned long long ms = __ballot(sane != 0);
    __shared__ int wz[4], wsn[4];
    if ((tid & 63) == 0) { wz[tid >> 6] = __popcll(mz); wsn[tid >> 6] = __popcll(ms); }
    __syncthreads();
    if (tid == 0) {
        const int nz = wz[0] + wz[1] + wz[2] + wz[3];
        const int ns = wsn[0] + wsn[1] + wsn[2] + wsn[3];
        flags[0] = (nz >= 192 || ns < 128) ? 1 : 0;
    }
}

// convert/copy one input array into canonical bf16 (n multiple of 8) [fallback]
__global__ __launch_bounds__(256) void convert_kernel(const void* __restrict__ src,
                                                      __bf16* __restrict__ dst, int n,
                                                      const int* __restrict__ flags) {
    const int i = (blockIdx.x * 256 + threadIdx.x) * 8;
    if (i >= n) return;
    if (flags[0]) {
        const float* s = (const float*)src;
        bf16x8 o;
#pragma unroll
        for (int j = 0; j < 8; j++) o[j] = (__bf16)s[i + j];
        *(bf16x8*)(dst + i) = o;
    } else {
        *(uint4*)(dst + i) = *(const uint4*)((const __bf16*)src + i);
    }
}

// ---------------------------------------------------------------------------
// Merged: fp32->bf16 convert of all 11 weight arrays AND LN1 in ONE kernel.
struct CvtJobs {
    const float* s[11];
    __bf16* d[11];
    int n[11];
    int b0[11];
};
struct CvtLn1 {
    CvtJobs J;
    const float* x;
    const float* g;
    const float* b;
    __bf16* out;
    int bcvt;
};
__global__ __launch_bounds__(256) void cvt_ln1_kernel(CvtLn1 P) {
    const int bid = blockIdx.x;
    const int tid = threadIdx.x;
    if (bid < P.bcvt) {
        int j = 0;
#pragma unroll
        for (int k = 1; k < 11; k++)
            if (bid >= P.J.b0[k]) j = k;
        const int i = (bid - P.J.b0[j]) * 2048 + tid * 8;
        if (i >= P.J.n[j]) return;
        const float* s = P.J.s[j] + i;
        bf16x8 o;
#pragma unroll
        for (int t = 0; t < 8; t++) o[t] = (__bf16)s[t];
        *(bf16x8*)(P.J.d[j] + i) = o;
        return;
    }
    const size_t row = (size_t)(bid - P.bcvt);
    const float* xr = P.x + row * 1024;
    float v[4];
#pragma unroll
    for (int i = 0; i < 4; i++) v[i] = xr[tid * 4 + i];
    float s = v[0] + v[1] + v[2] + v[3];
    float s2 = v[0] * v[0] + v[1] * v[1] + v[2] * v[2] + v[3] * v[3];
#pragma unroll
    for (int m = 32; m >= 1; m >>= 1) {
        s += __shfl_xor(s, m, 64);
        s2 += __shfl_xor(s2, m, 64);
    }
    __shared__ float rs[4], rs2[4];
    const int wave = tid >> 6, lane = tid & 63;
    if (lane == 0) { rs[wave] = s; rs2[wave] = s2; }
    __syncthreads();
    s = rs[0] + rs[1] + rs[2] + rs[3];
    s2 = rs2[0] + rs2[1] + rs2[2] + rs2[3];
    const float mu = s * (1.0f / 1024.0f);
    const float var = s2 * (1.0f / 1024.0f) - mu * mu;
    const float inv = rsqrtf(var + 1e-5f);
#pragma unroll
    for (int i = 0; i < 4; i++) {
        const int c = tid * 4 + i;
        P.out[row * 1024 + c] = (__bf16)((v[i] - mu) * inv * P.g[c] + P.b[c]);
    }
}

// ---------------------------------------------------------------------------
// LayerNorm: one block per row of 1024, fp32 math, bf16 out (LN2 + fallback)
template <typename T>
__global__ __launch_bounds__(256) void ln_kernel(const T* __restrict__ x,
                                                 const __bf16* __restrict__ g,
                                                 const __bf16* __restrict__ b,
                                                 __bf16* __restrict__ out) {
    const size_t row = blockIdx.x;
    const T* xr = x + row * 1024;
    const int tid = threadIdx.x;
    float v[4];
#pragma unroll
    for (int i = 0; i < 4; i++) v[i] = (float)xr[tid * 4 + i];
    float s = v[0] + v[1] + v[2] + v[3];
    float s2 = v[0] * v[0] + v[1] * v[1] + v[2] * v[2] + v[3] * v[3];
#pragma unroll
    for (int m = 32; m >= 1; m >>= 1) {
        s += __shfl_xor(s, m, 64);
        s2 += __shfl_xor(s2, m, 64);
    }
    __shared__ float rs[4], rs2[4];
    const int wave = tid >> 6, lane = tid & 63;
    if (lane == 0) { rs[wave] = s; rs2[wave] = s2; }
    __syncthreads();
    s = rs[0] + rs[1] + rs[2] + rs[3];
    s2 = rs2[0] + rs2[1] + rs2[2] + rs2[3];
    const float mu = s * (1.0f / 1024.0f);
    const float var = s2 * (1.0f / 1024.0f) - mu * mu;
    const float inv = rsqrtf(var + 1e-5f);
#pragma unroll
    for (int i = 0; i < 4; i++) {
        const int c = tid * 4 + i;
        out[row * 1024 + c] = (__bf16)((v[i] - mu) * inv * (float)g[c] + (float)b[c]);
    }
}

enum { EP_NONE = 0, EP_ELU1 = 1, EP_BIAS_GELU = 2, EP_BIAS_RES = 3, EP_QKV = 4 };

// ---------------------------------------------------------------------------
// 256x256 8-phase MFMA GEMM, round-18 (race-fixed; K%128==0 shapes).
// Round-17 FAILED correctness (absmax 398): its phase did vmcnt -> ds_read ->
// barrier, so waves read LDS staged by OTHER waves whose DMA hadn't landed
// (vmcnt is per-wave; only vmcnt -> barrier makes it global). Round-18 uses
// the proven KBODY ordering per phase:
//   { vmcnt(4|0)? -> s_barrier -> sched_barrier -> stage-pack -> ds_read
//     frags -> setprio(1) 16xMFMA setprio(0) }
// one barrier/phase (4/tile). Ledger (per-wave outstanding): entering tile i,
// 8 loads in flight = buf-X k0-pack (issued tile i-1 ph0) + k1-pack (ph1).
// ph0 vmcnt(4) drains the k0-pack (4 phases ~1600cy cover) before its reads;
// ph1 vmcnt(4) drains k1; ph2/3 no waits (data already barrier-published).
// Drain tile: ph0 vmcnt(4), ph1 vmcnt(0), no stage. Overwrite-safe: buf-Y
// reads finish before their phase's MFMA < next barrier < stage issue.
// Indexing identical to round-7's gemm256 (which PASSED correctness).
#define STG4(DA, DB, KOFF)                                  \
    do {                                                    \
        gload_lds16(sA0 + (KOFF), &DA[tid * 8]);            \
        gload_lds16(sA1 + (KOFF), &DA[4096 + tid * 8]);     \
        gload_lds16(sB0 + (KOFF), &DB[tid * 8]);            \
        gload_lds16(sB1 + (KOFF), &DB[4096 + tid * 8]);     \
    } while (0)

// VMN: 4 = steady wait, 0 = drain, -1 = none. READB: load fresh B frags.
#define PH256(RA, RB, FRB, READB, BV, DO_STG, SDA, SDB, KOFF, VMN)             \
    do {                                                                       \
        if ((VMN) == 4) asm volatile("s_waitcnt vmcnt(4)" ::: "memory");       \
        else if ((VMN) == 0) asm volatile("s_waitcnt vmcnt(0)" ::: "memory");  \
        __builtin_amdgcn_s_barrier();                                          \
        __builtin_amdgcn_sched_barrier(0);                                     \
        if (DO_STG) STG4(SDA, SDB, KOFF);                                      \
        bf16x8 a_[4];                                                          \
        if (READB)                                                             \
            _Pragma("unroll") for (int f_ = 0; f_ < 4; f_++)                   \
                BV[f_] = *(const bf16x8*)&RB[boff[f_]];                        \
        _Pragma("unroll") for (int f_ = 0; f_ < 4; f_++)                       \
            a_[f_] = *(const bf16x8*)&RA[aoff[(FRB) + f_]];                    \
        __builtin_amdgcn_s_setprio(1);                                         \
        _Pragma("unroll") for (int f_ = 0; f_ < 4; f_++)                       \
            _Pragma("unroll") for (int c_ = 0; c_ < 4; c_++)                   \
                acc[(FRB) + f_][c_] = __builtin_amdgcn_mfma_f32_16x16x32_bf16( \
                    a_[f_], BV[c_], acc[(FRB) + f_][c_], 0, 0, 0);             \
        __builtin_amdgcn_s_setprio(0);                                         \
    } while (0)

// one K-tile (BK=64): reads bufs {AX..}, stages tile KT into {AY..}.
// VM1 = ph1 wait (4 steady, 0 drain).
#define TILE256(AX0, AX1, BX0, BX1, AY0, AY1, BY0, BY1, KT, DO_STG, VM1)       \
    do {                                                                       \
        PH256(AX0, BX0, 0, 1, b0, DO_STG, AY0, BY0, (KT) * 64, 4);             \
        PH256(AX1, BX1, 0, 1, b1, DO_STG, AY1, BY1, (KT) * 64 + 32, VM1);      \
        PH256(AX0, BX0, 4, 0, b0, 0, AY0, BY0, 0, -1);                         \
        PH256(AX1, BX1, 4, 0, b1, 0, AY1, BY1, 0, -1);                         \
    } while (0)

template <int EP>
__global__ __launch_bounds__(512) void gemm256(
    const __bf16* __restrict__ A, const __bf16* __restrict__ B,
    const __bf16* __restrict__ bias, __bf16* __restrict__ out2,
    __bf16* __restrict__ out3, __bf16* __restrict__ C, int M, int N, int K) {
    const int gx = gridDim.x, gy = gridDim.y;
    int bm = blockIdx.y, bn = blockIdx.x;
    {
        const int nwg = gx * gy;
        const int bid = bm * gx + bn;
        if ((gx & 7) == 0 && (nwg & 63) == 0) {  // 8x8 super-tile per XCD
            const int perx = nwg >> 3;
            const int gid = (bid & 7) * perx + (bid >> 3);
            const int stg = gid >> 6, pos = gid & 63;
            const int stw = gx >> 3;
            bm = (stg / stw) * 8 + (pos >> 3);
            bn = (stg % stw) * 8 + (pos & 7);
        } else if ((nwg & 7) == 0) {             // 1-D bijective fallback
            const int perx = nwg >> 3;
            const int gid = (bid & 7) * perx + (bid >> 3);
            bm = gid / gx;
            bn = gid % gx;
        }
    }
    const int tid = threadIdx.x;
    const int wave = tid >> 6, lane = tid & 63;
    const int wr = wave >> 2, wc = wave & 3;  // 2 (M) x 4 (N)
    const int lm = lane & 15, lq = lane >> 4;

    __shared__ __align__(16) __bf16 A0k0[8192];
    __shared__ __align__(16) __bf16 A0k1[8192];
    __shared__ __align__(16) __bf16 B0k0[8192];
    __shared__ __align__(16) __bf16 B0k1[8192];
    __shared__ __align__(16) __bf16 A1k0[8192];
    __shared__ __align__(16) __bf16 A1k1[8192];
    __shared__ __align__(16) __bf16 B1k0[8192];
    __shared__ __align__(16) __bf16 B1k1[8192];

    f32x4 acc[8][4] = {};
    bf16x8 b0[4], b1[4];

    // per-lane swizzled LDS elem offsets into [256][32] arrays
    const int swz = (lq ^ ((lm >> 1) & 3)) << 3;
    int aoff[8], boff[4];
#pragma unroll
    for (int fr = 0; fr < 8; fr++) aoff[fr] = (wr * 128 + fr * 16 + lm) * 32 + swz;
#pragma unroll
    for (int fc = 0; fc < 4; fc++) boff[fc] = (wc * 64 + fc * 16 + lm) * 32 + swz;

    // staging: thread tid -> row tid>>2 (per 128-row gload half), slot tid&3;
    // source col-group (tid&3)^((tid>>3)&3) (inverse involution, coalesced).
    const int srow = tid >> 2;
    const int sg = (((tid & 3) ^ ((tid >> 3) & 3)) << 3);
    const __bf16* sA0 = A + (size_t)(bm * 256 + srow) * K + sg;
    const __bf16* sA1 = sA0 + (size_t)128 * K;
    const __bf16* sB0 = B + (size_t)(bn * 256 + srow) * K + sg;
    const __bf16* sB1 = sB0 + (size_t)128 * K;

    const int nt = K >> 6;  // requires even, >= 2 (K=1024 -> 16)

    // prologue: stage tile 0 (k0-pack then k1-pack; 8 loads in flight)
    STG4(A0k0, B0k0, 0);
    STG4(A0k1, B0k1, 32);

    int t = 0;
    for (; t + 2 < nt; t += 2) {
        TILE256(A0k0, A0k1, B0k0, B0k1, A1k0, A1k1, B1k0, B1k1, t + 1, 1, 4);
        TILE256(A1k0, A1k1, B1k0, B1k1, A0k0, A0k1, B0k0, B0k1, t + 2, 1, 4);
    }
    TILE256(A0k0, A0k1, B0k0, B0k1, A1k0, A1k1, B1k0, B1k1, t + 1, 1, 4);
    TILE256(A1k0, A1k1, B1k0, B1k1, A0k0, A0k1, B0k0, B0k1, 0, 0, 0);  // drain

    // epilogue
    const int rowb = bm * 256 + wr * 128 + lq * 4;
    const int colb = bn * 256 + wc * 64 + lm;
#pragma unroll
    for (int fr = 0; fr < 8; fr++) {
#pragma unroll
        for (int fc = 0; fc < 4; fc++) {
            const int col = colb + fc * 16;
#pragma unroll
            for (int r = 0; r < 4; r++) {
                const int row = rowb + fr * 16 + r;
                float v = acc[fr][fc][r];
                if (EP == EP_QKV) {
                    float vv = (col < 2048) ? ((v > 0.0f) ? (v + 1.0f) : expf(v)) : v;
                    __bf16* dst = (col < 1024) ? C : (col < 2048) ? out2 : out3;
                    dst[(size_t)row * 1024 + (col & 1023)] = (__bf16)vv;
                } else {  // EP_BIAS_GELU
                    v += (float)bias[col];
                    v = 0.5f * v * (1.0f + erf_fast(v * 0.70710678118654752f));
                    C[(size_t)row * N + col] = (__bf16)v;
                }
            }
        }
    }
}

// ---------------------------------------------------------------------------
// 128x128 2-phase pipelined GEMM (round-8 proven) -- MLP2 + fallback path.
#define READMM(RA, RB)                                                            \
    do {                                                                          \
        bf16x8 af_[BM / 32], bfv_[4];                                             \
        _Pragma("unroll") for (int i_ = 0; i_ < BM / 32; i_++)                    \
            af_[i_] = *(const bf16x8*)&RA[(wm * (BM / 2) + i_ * 16 + lm) * 32 + swz]; \
        _Pragma("unroll") for (int j_ = 0; j_ < 4; j_++)                          \
            bfv_[j_] = *(const bf16x8*)&RB[(wn * 64 + j_ * 16 + lm) * 32 + swz];  \
        _Pragma("unroll") for (int i_ = 0; i_ < BM / 32; i_++)                    \
            _Pragma("unroll") for (int j_ = 0; j_ < 4; j_++)                      \
                acc[i_][j_] = __builtin_amdgcn_mfma_f32_16x16x32_bf16(            \
                    af_[i_], bfv_[j_], acc[i_][j_], 0, 0, 0);                     \
    } while (0)

#define KBODY(RA, RB, SA, SB, TS)                                  \
    do {                                                           \
        if constexpr (BM == 128)                                   \
            asm volatile("s_waitcnt vmcnt(4)" ::: "memory");       \
        else                                                       \
            asm volatile("s_waitcnt vmcnt(3)" ::: "memory");       \
        __builtin_amdgcn_s_barrier();                              \
        __builtin_amdgcn_sched_barrier(0);                         \
        if ((TS) < nt) {                                           \
            const int k0_ = (TS) << 5;                             \
            gload_lds16(pa0 + k0_, &SA[tid * 8]);                  \
            if constexpr (BM == 128)                               \
                gload_lds16(pa1 + k0_, &SA[2048 + tid * 8]);       \
            gload_lds16(pb0 + k0_, &SB[tid * 8]);                  \
            gload_lds16(pb1 + k0_, &SB[2048 + tid * 8]);           \
        }                                                          \
        __builtin_amdgcn_s_setprio(1);                             \
        READMM(RA, RB);                                            \
        __builtin_amdgcn_s_setprio(0);                             \
    } while (0)

template <int EP, int BM, typename OutT>
__global__ __launch_bounds__(256, 3) void gemm_bt(
    const __bf16* __restrict__ A, const __bf16* __restrict__ B,
    const __bf16* __restrict__ bias, const float* __restrict__ resid,
    OutT* __restrict__ C, int M, int N, int K) {
    const int gx = gridDim.x, gy = gridDim.y;
    int bm = blockIdx.y, bn = blockIdx.x;
    {
        const int nwg = gx * gy;
        if ((gx & 7) == 0 && (nwg & 63) == 0) {
            const int bid = bm * gx + bn;
            const int perx = nwg >> 3;
            const int gid = (bid & 7) * perx + (bid >> 3);
            const int stg = gid >> 6, pos = gid & 63;
            const int stw = gx >> 3;
            bm = (stg / stw) * 8 + (pos >> 3);
            bn = (stg % stw) * 8 + (pos & 7);
        }
    }
    const int tid = threadIdx.x;
    const int wave = tid >> 6, lane = tid & 63;
    const int wm = wave & 1, wn = wave >> 1;
    const int lm = lane & 15, lq = lane >> 4;
    const int swz = (lq ^ ((lm >> 1) & 3)) * 8;

    __shared__ __align__(16) __bf16 As0[BM * 32];
    __shared__ __align__(16) __bf16 As1[BM * 32];
    __shared__ __align__(16) __bf16 As2[BM * 32];
    __shared__ __align__(16) __bf16 Bs0[128 * 32];
    __shared__ __align__(16) __bf16 Bs1[128 * 32];
    __shared__ __align__(16) __bf16 Bs2[128 * 32];

    f32x4 acc[BM / 32][4] = {};

    const int sr = tid >> 2;
    const int sc = (((tid & 3) ^ ((tid >> 3) & 3)) << 3);

    const __bf16* pa0 = A + (size_t)(bm * BM + sr) * K + sc;
    const __bf16* pa1 = pa0 + (size_t)(BM == 128 ? 64 : 0) * K;
    const __bf16* pb0 = B + (size_t)(bn * 128 + sr) * K + sc;
    const __bf16* pb1 = pb0 + (size_t)64 * K;

    const int nt = K >> 5;

    gload_lds16(pa0, &As0[tid * 8]);
    if constexpr (BM == 128) gload_lds16(pa1, &As0[2048 + tid * 8]);
    gload_lds16(pb0, &Bs0[tid * 8]);
    gload_lds16(pb1, &Bs0[2048 + tid * 8]);
    if (nt > 1) {
        gload_lds16(pa0 + 32, &As1[tid * 8]);
        if constexpr (BM == 128) gload_lds16(pa1 + 32, &As1[2048 + tid * 8]);
        gload_lds16(pb0 + 32, &Bs1[tid * 8]);
        gload_lds16(pb1 + 32, &Bs1[2048 + tid * 8]);
    }

    int t = 0;
    for (; t + 2 < nt; t += 3) {
        KBODY(As0, Bs0, As2, Bs2, t + 2);
        KBODY(As1, Bs1, As0, Bs0, t + 3);
        KBODY(As2, Bs2, As1, Bs1, t + 4);
    }
    if (t < nt) {
        asm volatile("s_waitcnt vmcnt(0)" ::: "memory");
        __builtin_amdgcn_s_barrier();
        __builtin_amdgcn_sched_barrier(0);
        READMM(As0, Bs0);
        t++;
        if (t < nt) { READMM(As1, Bs1); }
    }

    const int row0 = bm * BM + wm * (BM / 2);
    const int col0 = bn * 128 + wn * 64;
#pragma unroll
    for (int i = 0; i < BM / 32; i++) {
#pragma unroll
        for (int j = 0; j < 4; j++) {
            const int col = col0 + j * 16 + lm;
#pragma unroll
            for (int r = 0; r < 4; r++) {
                const int row = row0 + i * 16 + lq * 4 + r;
                float v = acc[i][j][r];
                if (EP == EP_QKV) {
                    float vv = (col < 2048) ? ((v > 0.0f) ? (v + 1.0f) : expf(v)) : v;
                    __bf16* dst = (col < 1024) ? (__bf16*)C
                                : (col < 2048) ? (__bf16*)const_cast<__bf16*>(bias)
                                               : (__bf16*)const_cast<float*>(resid);
                    dst[(size_t)row * 1024 + (col & 1023)] = (__bf16)vv;
                } else {
                    if (EP == EP_ELU1) {
                        v = (v > 0.0f) ? (v + 1.0f) : expf(v);
                    } else if (EP == EP_BIAS_GELU) {
                        v += (float)bias[col];
                        v = 0.5f * v * (1.0f + erf_fast(v * 0.70710678118654752f));
                    } else if (EP == EP_BIAS_RES) {
                        v += (float)bias[col];
                        v += resid[(size_t)row * N + col];
                    }
                    C[(size_t)row * N + col] = (OutT)v;
                }
            }
        }
    }
}

// ---------------------------------------------------------------------------
// KV partials + 1024-block reduce (round-8 proven).
__global__ __launch_bounds__(256) void kv_kernel(const __bf16* __restrict__ Kf,
                                                 const __bf16* __restrict__ Vf,
                                                 float* __restrict__ pkv,
                                                 float* __restrict__ pks) {
    const int nh = blockIdx.x, sc = blockIdx.y;
    const int n = nh >> 3, h = nh & 7;
    const int tid = threadIdx.x;
    const int tv = tid & 15, td = tid >> 4;
    __shared__ __align__(16) __bf16 Kt[32 * 128];
    __shared__ __align__(16) __bf16 Vt[32 * 128];
    float acc[8][8] = {};
    float ks[8] = {};
    const size_t rowbase = (size_t)n * 4096 + (size_t)sc * 256;
    for (int s0 = 0; s0 < 256; s0 += 32) {
#pragma unroll
        for (int rep = 0; rep < 2; rep++) {
            const int s = tid + rep * 256;
            const int r = s >> 4, cs = (s & 15) * 8;
            const size_t gidx = (rowbase + s0 + r) * 1024 + h * 128 + cs;
            *(bf16x8*)&Kt[r * 128 + cs] = *(const bf16x8*)&Kf[gidx];
            *(bf16x8*)&Vt[r * 128 + cs] = *(const bf16x8*)&Vf[gidx];
        }
        __syncthreads();
#pragma unroll 4
        for (int s = 0; s < 32; s++) {
            const bf16x8 k8 = *(const bf16x8*)&Kt[s * 128 + td * 8];
            const bf16x8 v8 = *(const bf16x8*)&Vt[s * 128 + tv * 8];
            float kk[8], vv[8];
#pragma unroll
            for (int i = 0; i < 8; i++) { kk[i] = (float)k8[i]; vv[i] = (float)v8[i]; }
#pragma unroll
            for (int i = 0; i < 8; i++) {
                ks[i] += kk[i];
#pragma unroll
                for (int j = 0; j < 8; j++) acc[i][j] += kk[i] * vv[j];
            }
        }
        __syncthreads();
    }
    float* dst = pkv + ((size_t)sc * 16 + nh) * 16384;
#pragma unroll
    for (int i = 0; i < 8; i++)
#pragma unroll
        for (int j = 0; j < 8; j++)
            dst[(td * 8 + i) * 128 + tv * 8 + j] = acc[i][j];
    if (tv == 0) {
        float* ds2 = pks + ((size_t)sc * 16 + nh) * 128;
#pragma unroll
        for (int i = 0; i < 8; i++) ds2[td * 8 + i] = ks[i];
    }
}

__global__ __launch_bounds__(256) void kv_reduce(const float* __restrict__ pkv,
                                                 const float* __restrict__ pks,
                                                 __bf16* __restrict__ kvb,
                                                 float* __restrict__ ksf) {
    const int idx = blockIdx.x * 256 + threadIdx.x;
    float s = 0.0f;
#pragma unroll
    for (int c = 0; c < 16; c++) s += pkv[(size_t)c * 262144 + idx];
    kvb[idx] = (__bf16)s;
    if (idx < 2048) {
        float t = 0.0f;
#pragma unroll
        for (int c = 0; c < 16; c++) t += pks[c * 2048 + idx];
        ksf[idx] = t;
    }
}

// attn out + residual, z fused. x dtype templated.
template <typename XT>
__global__ __launch_bounds__(256, 2) void attn_out_kernel(
    const XT* __restrict__ x, const __bf16* __restrict__ Qf,
    const __bf16* __restrict__ kvb, const float* __restrict__ ksf,
    float* __restrict__ xmid) {
    const int nh = blockIdx.x, lc = blockIdx.y;
    const int n = nh >> 3, h = nh & 7;
    const int tid = threadIdx.x;
    __shared__ __align__(16) __bf16 KVs[128 * 128];
    __shared__ __align__(16) __bf16 Qs[64 * 128];
    __shared__ float Ks[128];
    const __bf16* kv = kvb + (size_t)nh * 16384;
    for (int i = tid * 8; i < 16384; i += 2048)
        *(bf16x8*)&KVs[i] = *(const bf16x8*)&kv[i];
    const size_t gr0 = (size_t)n * 4096 + (size_t)lc * 64;
#pragma unroll
    for (int rep = 0; rep < 4; rep++) {
        const int s = tid + rep * 256;
        const int r = s >> 4, cs = (s & 15) * 8;
        *(bf16x8*)&Qs[r * 128 + cs] = *(const bf16x8*)&Qf[(gr0 + r) * 1024 + h * 128 + cs];
    }
    if (tid < 128) Ks[tid] = ksf[(size_t)nh * 128 + tid];
    __syncthreads();
    const int tv = (tid & 15) * 8;
    const int tr0 = (tid >> 4) * 4;
    float acc[4][8] = {};
    float zs[4] = {};
    for (int d = 0; d < 128; d++) {
        const bf16x8 kv8 = *(const bf16x8*)&KVs[d * 128 + tv];
        const float ksd = Ks[d];
        float kf[8];
#pragma unroll
        for (int j = 0; j < 8; j++) kf[j] = (float)kv8[j];
#pragma unroll
        for (int rr = 0; rr < 4; rr++) {
            const float q = (float)Qs[(tr0 + rr) * 128 + d];
            zs[rr] += q * ksd;
#pragma unroll
            for (int j = 0; j < 8; j++) acc[rr][j] += q * kf[j];
        }
    }
#pragma unroll
    for (int rr = 0; rr < 4; rr++) {
        const size_t gi = (gr0 + tr0 + rr) * 1024 + h * 128 + tv;
        const float z = 1.0f / (zs[rr] + 1e-6f);
        const XT* xr = x + gi;
#pragma unroll
        for (int j = 0; j < 8; j++) xmid[gi + j] = (float)xr[j] + acc[rr][j] * z;
    }
}

// ---------------------------------------------------------------------------
extern "C" void kernel_launch(void* const* d_in, const int* in_sizes, int n_in,
                              void* d_out, int out_size, void* d_ws, size_t ws_size,
                              hipStream_t stream) {
    float* out = (float*)d_out;   // output is FP32 (reference output dtype)
    char* ws = (char*)d_ws;

    const int nx = 8388608, nw = 1048576, nw1 = 4194304, nb1 = 4096, ng = 1024;
    size_t off = 0;
    __bf16* cx   = (__bf16*)(ws + off); off += (size_t)nx * 2;
    __bf16* cwq  = (__bf16*)(ws + off); off += (size_t)nw * 2;   // cwq/cwk/cwv
    __bf16* cwk  = (__bf16*)(ws + off); off += (size_t)nw * 2;   // contiguous =
    __bf16* cwv  = (__bf16*)(ws + off); off += (size_t)nw * 2;   // B[3072,1024]
    __bf16* cw1  = (__bf16*)(ws + off); off += (size_t)nw1 * 2;
    __bf16* cb1  = (__bf16*)(ws + off); off += (size_t)nb1 * 2;
    __bf16* cw2  = (__bf16*)(ws + off); off += (size_t)nw1 * 2;
    __bf16* cb2  = (__bf16*)(ws + off); off += (size_t)ng * 2;
    __bf16* cg1  = (__bf16*)(ws + off); off += (size_t)ng * 2;
    __bf16* cbe1 = (__bf16*)(ws + off); off += (size_t)ng * 2;
    __bf16* cg2  = (__bf16*)(ws + off); off += (size_t)ng * 2;
    __bf16* cbe2 = (__bf16*)(ws + off); off += (size_t)ng * 2;
    int* flags = (int*)(ws + off); off += 64;

    char* PB = ws + off;
    __bf16* x2   = (__bf16*)(PB);                 // LN1 out; later LN2 out
    float*  pkv  = (float*)(PB + 33554432);
    __bf16* Qf   = (__bf16*)(PB + 16777216);
    __bf16* hbuf = (__bf16*)(PB + 16777216);      // MLP h chunk (over Qf+pkv)
    __bf16* Kf   = (__bf16*)(PB + 50331648);
    __bf16* Vf   = (__bf16*)(PB + 67108864);
    float*  xmid = (float*)(PB + 50331648);       // fp32 (over Kf/Vf)
    float*  pks  = (float*)(PB + 83886080);
    float*  ksf  = (float*)(PB + 84017152);
    __bf16* kvb  = (__bf16*)(PB + 84287488);      // ends PB+84,811,776
    __bf16* hbig = (__bf16*)(PB + 84811776);      // 64MB full-M hbuf (optional)
    const size_t need_single = (size_t)(PB - ws) + 84811776 + (size_t)8192 * 4096 * 2;
    const bool single_mlp = ws_size >= need_single;

    // 0+1. canonicalize weights + LN1 (merged when fp32 inputs).
    const bool is_f32 = (in_sizes[0] == nx * 4);
    if (is_f32) {
        CvtLn1 P;
        const float* srcs[11] = {(const float*)d_in[1], (const float*)d_in[2],
                                 (const float*)d_in[3], (const float*)d_in[4],
                                 (const float*)d_in[5], (const float*)d_in[6],
                                 (const float*)d_in[7], (const float*)d_in[8],
                                 (const float*)d_in[9], (const float*)d_in[10],
                                 (const float*)d_in[11]};
        __bf16* dsts[11] = {cwq, cwk, cwv, cw1, cb1, cw2, cb2, cg1, cbe1, cg2, cbe2};
        int ns[11] = {nw, nw, nw, nw1, nb1, nw1, ng, ng, ng, ng, ng};
        int b = 0;
        for (int k = 0; k < 11; k++) {
            P.J.s[k] = srcs[k]; P.J.d[k] = dsts[k]; P.J.n[k] = ns[k]; P.J.b0[k] = b;
            b += (ns[k] + 2047) / 2048;
        }
        P.x = (const float*)d_in[0];
        P.g = (const float*)d_in[8];
        P.b = (const float*)d_in[9];
        P.out = x2;
        P.bcvt = b;
        cvt_ln1_kernel<<<b + 8192, 256, 0, stream>>>(P);
    } else {
        sniff_kernel<<<1, 256, 0, stream>>>((const unsigned short*)d_in[0], flags);
        convert_kernel<<<nx / 2048, 256, 0, stream>>>(d_in[0], cx, nx, flags);
        convert_kernel<<<nw / 2048, 256, 0, stream>>>(d_in[1], cwq, nw, flags);
        convert_kernel<<<nw / 2048, 256, 0, stream>>>(d_in[2], cwk, nw, flags);
        convert_kernel<<<nw / 2048, 256, 0, stream>>>(d_in[3], cwv, nw, flags);
        convert_kernel<<<nw1 / 2048, 256, 0, stream>>>(d_in[4], cw1, nw1, flags);
        convert_kernel<<<2, 256, 0, stream>>>(d_in[5], cb1, nb1, flags);
        convert_kernel<<<nw1 / 2048, 256, 0, stream>>>(d_in[6], cw2, nw1, flags);
        convert_kernel<<<1, 256, 0, stream>>>(d_in[7], cb2, ng, flags);
        convert_kernel<<<1, 256, 0, stream>>>(d_in[8], cg1, ng, flags);
        convert_kernel<<<1, 256, 0, stream>>>(d_in[9], cbe1, ng, flags);
        convert_kernel<<<1, 256, 0, stream>>>(d_in[10], cg2, ng, flags);
        convert_kernel<<<1, 256, 0, stream>>>(d_in[11], cbe2, ng, flags);
        ln_kernel<__bf16><<<8192, 256, 0, stream>>>(cx, cg1, cbe1, x2);
    }

    // 2. fused QKV projection via race-fixed 8-phase 256x256 GEMM
    gemm256<EP_QKV><<<dim3(3072 / 256, 8192 / 256), 512, 0, stream>>>(
        x2, cwq, nullptr, Kf, Vf, Qf, 8192, 3072, 1024);

    // 3. KV + Ksum (non-atomic partials + 1024-block reduce)
    kv_kernel<<<dim3(16, 16), 256, 0, stream>>>(Kf, Vf, pkv, pks);
    kv_reduce<<<1024, 256, 0, stream>>>(pkv, pks, kvb, ksf);

    // 4. attention out (z fused) + residual -> xmid fp32 (over dead Kf/Vf)
    if (is_f32)
        attn_out_kernel<float><<<dim3(16, 64), 256, 0, stream>>>(
            (const float*)d_in[0], Qf, kvb, ksf, xmid);
    else
        attn_out_kernel<__bf16><<<dim3(16, 64), 256, 0, stream>>>(
            cx, Qf, kvb, ksf, xmid);

    // 5. LN2 + MLP. MLP1 on 8-phase gemm256 (K=1024); MLP2 stays 2-phase.
    ln_kernel<float><<<8192, 256, 0, stream>>>(xmid, cg2, cbe2, x2);
    if (single_mlp) {
        gemm256<EP_BIAS_GELU><<<dim3(4096 / 256, 8192 / 256), 512, 0, stream>>>(
            x2, cw1, cb1, nullptr, nullptr, hbig, 8192, 4096, 1024);
        gemm_bt<EP_BIAS_RES, 128, float><<<dim3(1024 / 128, 8192 / 128), 256, 0, stream>>>(
            hbig, cw2, cb2, xmid, out, 8192, 1024, 4096);
    } else {
        for (int c = 0; c < 2; c++) {
            const size_t ro = (size_t)c * 4096;
            gemm_bt<EP_BIAS_GELU, 128, __bf16><<<dim3(4096 / 128, 4096 / 128), 256, 0, stream>>>(
                x2 + ro * 1024, cw1, cb1, nullptr, hbuf, 4096, 4096, 1024);
            gemm_bt<EP_BIAS_RES, 64, float><<<dim3(1024 / 128, 4096 / 64), 256, 0, stream>>>(
                hbuf, cw2, cb2, xmid + ro * 1024, out + ro * 1024, 4096, 1024, 4096);
        }
    }
}

// Round 19
// 394.454 us; speedup vs baseline: 1.0687x; 1.0687x over previous
//
#include <hip/hip_runtime.h>
#include <hip/hip_bf16.h>
#include <math.h>

typedef __bf16 bf16x8 __attribute__((ext_vector_type(8)));
typedef float f32x4 __attribute__((ext_vector_type(4)));

#define DEVI __device__ __forceinline__

// async global->LDS, 16B per lane. LDS dest must be wave-uniform-base + lane*16.
DEVI void gload_lds16(const __bf16* g, __bf16* l) {
    __builtin_amdgcn_global_load_lds(
        (const __attribute__((address_space(1))) void*)g,
        (__attribute__((address_space(3))) void*)l, 16, 0, 0);
}

// branchless erf, Abramowitz-Stegun 7.1.26 (round-14 verified: -12us on MLP1)
DEVI float erf_fast(float y) {
    const float ay = fabsf(y);
    const float t = __builtin_amdgcn_rcpf(fmaf(0.3275911f, ay, 1.0f));
    float p = 1.061405429f;
    p = fmaf(p, t, -1.453152027f);
    p = fmaf(p, t, 1.421413741f);
    p = fmaf(p, t, -0.284496736f);
    p = fmaf(p, t, 0.254829592f);
    p = p * t;
    const float e = exp2f(-y * y * 1.4426950408889634f);
    return copysignf(1.0f - p * e, y);
}

// ---------------------------------------------------------------------------
// dtype sniffer (2-byte fallback path only). flag[0]=1 -> fp32 storage.
__global__ void sniff_kernel(const unsigned short* __restrict__ x, int* flags) {
    const int tid = threadIdx.x;  // 256
    const unsigned short u = x[tid * 2];
    const int e = (u >> 7) & 0xFF;
    const int zero = (u == 0) ? 1 : 0;
    const int sane = ((e >= 0x71 && e <= 0x8E) || ((u & 0x7FFF) == 0)) ? 1 : 0;
    const unsigned long long mz = __ballot(zero != 0);
    const unsigned long long ms = __ballot(sane != 0);
    __shared__ int wz[4], wsn[4];
    if ((tid & 63) == 0) { wz[tid >> 6] = __popcll(mz); wsn[tid >> 6] = __popcll(ms); }
    __syncthreads();
    if (tid == 0) {
        const int nz = wz[0] + wz[1] + wz[2] + wz[3];
        const int ns = wsn[0] + wsn[1] + wsn[2] + wsn[3];
        flags[0] = (nz >= 192 || ns < 128) ? 1 : 0;
    }
}

// convert/copy one input array into canonical bf16 (n multiple of 8) [fallback]
__global__ __launch_bounds__(256) void convert_kernel(const void* __restrict__ src,
                                                      __bf16* __restrict__ dst, int n,
                                                      const int* __restrict__ flags) {
    const int i = (blockIdx.x * 256 + threadIdx.x) * 8;
    if (i >= n) return;
    if (flags[0]) {
        const float* s = (const float*)src;
        bf16x8 o;
#pragma unroll
        for (int j = 0; j < 8; j++) o[j] = (__bf16)s[i + j];
        *(bf16x8*)(dst + i) = o;
    } else {
        *(uint4*)(dst + i) = *(const uint4*)((const __bf16*)src + i);
    }
}

// ---------------------------------------------------------------------------
// Merged: fp32->bf16 convert of all 11 weight arrays AND LN1 in ONE kernel.
struct CvtJobs {
    const float* s[11];
    __bf16* d[11];
    int n[11];
    int b0[11];
};
struct CvtLn1 {
    CvtJobs J;
    const float* x;
    const float* g;
    const float* b;
    __bf16* out;
    int bcvt;
};
__global__ __launch_bounds__(256) void cvt_ln1_kernel(CvtLn1 P) {
    const int bid = blockIdx.x;
    const int tid = threadIdx.x;
    if (bid < P.bcvt) {
        int j = 0;
#pragma unroll
        for (int k = 1; k < 11; k++)
            if (bid >= P.J.b0[k]) j = k;
        const int i = (bid - P.J.b0[j]) * 2048 + tid * 8;
        if (i >= P.J.n[j]) return;
        const float* s = P.J.s[j] + i;
        bf16x8 o;
#pragma unroll
        for (int t = 0; t < 8; t++) o[t] = (__bf16)s[t];
        *(bf16x8*)(P.J.d[j] + i) = o;
        return;
    }
    const size_t row = (size_t)(bid - P.bcvt);
    const float* xr = P.x + row * 1024;
    float v[4];
#pragma unroll
    for (int i = 0; i < 4; i++) v[i] = xr[tid * 4 + i];
    float s = v[0] + v[1] + v[2] + v[3];
    float s2 = v[0] * v[0] + v[1] * v[1] + v[2] * v[2] + v[3] * v[3];
#pragma unroll
    for (int m = 32; m >= 1; m >>= 1) {
        s += __shfl_xor(s, m, 64);
        s2 += __shfl_xor(s2, m, 64);
    }
    __shared__ float rs[4], rs2[4];
    const int wave = tid >> 6, lane = tid & 63;
    if (lane == 0) { rs[wave] = s; rs2[wave] = s2; }
    __syncthreads();
    s = rs[0] + rs[1] + rs[2] + rs[3];
    s2 = rs2[0] + rs2[1] + rs2[2] + rs2[3];
    const float mu = s * (1.0f / 1024.0f);
    const float var = s2 * (1.0f / 1024.0f) - mu * mu;
    const float inv = rsqrtf(var + 1e-5f);
#pragma unroll
    for (int i = 0; i < 4; i++) {
        const int c = tid * 4 + i;
        P.out[row * 1024 + c] = (__bf16)((v[i] - mu) * inv * P.g[c] + P.b[c]);
    }
}

// ---------------------------------------------------------------------------
// LayerNorm: one block per row of 1024, fp32 math, bf16 out (LN2 + fallback)
template <typename T>
__global__ __launch_bounds__(256) void ln_kernel(const T* __restrict__ x,
                                                 const __bf16* __restrict__ g,
                                                 const __bf16* __restrict__ b,
                                                 __bf16* __restrict__ out) {
    const size_t row = blockIdx.x;
    const T* xr = x + row * 1024;
    const int tid = threadIdx.x;
    float v[4];
#pragma unroll
    for (int i = 0; i < 4; i++) v[i] = (float)xr[tid * 4 + i];
    float s = v[0] + v[1] + v[2] + v[3];
    float s2 = v[0] * v[0] + v[1] * v[1] + v[2] * v[2] + v[3] * v[3];
#pragma unroll
    for (int m = 32; m >= 1; m >>= 1) {
        s += __shfl_xor(s, m, 64);
        s2 += __shfl_xor(s2, m, 64);
    }
    __shared__ float rs[4], rs2[4];
    const int wave = tid >> 6, lane = tid & 63;
    if (lane == 0) { rs[wave] = s; rs2[wave] = s2; }
    __syncthreads();
    s = rs[0] + rs[1] + rs[2] + rs[3];
    s2 = rs2[0] + rs2[1] + rs2[2] + rs2[3];
    const float mu = s * (1.0f / 1024.0f);
    const float var = s2 * (1.0f / 1024.0f) - mu * mu;
    const float inv = rsqrtf(var + 1e-5f);
#pragma unroll
    for (int i = 0; i < 4; i++) {
        const int c = tid * 4 + i;
        out[row * 1024 + c] = (__bf16)((v[i] - mu) * inv * (float)g[c] + (float)b[c]);
    }
}

// ---------------------------------------------------------------------------
// MFMA GEMM: C[M,N] = A[M,K] @ B[N,K]^T, bf16 in, fp32 acc, OutT out.
// BMx128 tile, BK=32, 256 threads (4 waves 2x2). Round-8 proven structure:
// 3 distinct LDS buffers, K-loop unrolled x3, counted vmcnt; T2 both-sides
// swizzle (PMC 0 conflicts); T5 setprio; XCD 8x8 super-tile swizzle;
// branchless erf GELU. (8-phase 256x256 attempted rounds 7/17/18: regressed
// or raced every time at these shapes -- 1 block/CU lockstep; retired.)
enum { EP_NONE = 0, EP_ELU1 = 1, EP_BIAS_GELU = 2, EP_BIAS_RES = 3, EP_QKV = 4 };

#define READMM(RA, RB)                                                            \
    do {                                                                          \
        bf16x8 af_[BM / 32], bfv_[4];                                             \
        _Pragma("unroll") for (int i_ = 0; i_ < BM / 32; i_++)                    \
            af_[i_] = *(const bf16x8*)&RA[(wm * (BM / 2) + i_ * 16 + lm) * 32 + swz]; \
        _Pragma("unroll") for (int j_ = 0; j_ < 4; j_++)                          \
            bfv_[j_] = *(const bf16x8*)&RB[(wn * 64 + j_ * 16 + lm) * 32 + swz];  \
        _Pragma("unroll") for (int i_ = 0; i_ < BM / 32; i_++)                    \
            _Pragma("unroll") for (int j_ = 0; j_ < 4; j_++)                      \
                acc[i_][j_] = __builtin_amdgcn_mfma_f32_16x16x32_bf16(            \
                    af_[i_], bfv_[j_], acc[i_][j_], 0, 0, 0);                     \
    } while (0)

#define KBODY(RA, RB, SA, SB, TS)                                  \
    do {                                                           \
        if constexpr (BM == 128)                                   \
            asm volatile("s_waitcnt vmcnt(4)" ::: "memory");       \
        else                                                       \
            asm volatile("s_waitcnt vmcnt(3)" ::: "memory");       \
        __builtin_amdgcn_s_barrier();                              \
        __builtin_amdgcn_sched_barrier(0);                         \
        if ((TS) < nt) {                                           \
            const int k0_ = (TS) << 5;                             \
            gload_lds16(pa0 + k0_, &SA[tid * 8]);                  \
            if constexpr (BM == 128)                               \
                gload_lds16(pa1 + k0_, &SA[2048 + tid * 8]);       \
            gload_lds16(pb0 + k0_, &SB[tid * 8]);                  \
            gload_lds16(pb1 + k0_, &SB[2048 + tid * 8]);           \
        }                                                          \
        __builtin_amdgcn_s_setprio(1);                             \
        READMM(RA, RB);                                            \
        __builtin_amdgcn_s_setprio(0);                             \
    } while (0)

template <int EP, int BM, typename OutT>
__global__ __launch_bounds__(256, 3) void gemm_bt(
    const __bf16* __restrict__ A, const __bf16* __restrict__ B,
    const __bf16* __restrict__ bias, const float* __restrict__ resid,
    OutT* __restrict__ C, int M, int N, int K) {
    const int gx = gridDim.x, gy = gridDim.y;
    int bm = blockIdx.y, bn = blockIdx.x;
    {   // bijective XCD-chunked 8x8 super-tile remap (requires gx%8==0, nwg%64==0)
        const int nwg = gx * gy;
        if ((gx & 7) == 0 && (nwg & 63) == 0) {
            const int bid = bm * gx + bn;
            const int perx = nwg >> 3;
            const int gid = (bid & 7) * perx + (bid >> 3);
            const int stg = gid >> 6, pos = gid & 63;
            const int stw = gx >> 3;
            bm = (stg / stw) * 8 + (pos >> 3);
            bn = (stg % stw) * 8 + (pos & 7);
        }
    }
    const int tid = threadIdx.x;
    const int wave = tid >> 6, lane = tid & 63;
    const int wm = wave & 1, wn = wave >> 1;
    const int lm = lane & 15, lq = lane >> 4;
    const int swz = (lq ^ ((lm >> 1) & 3)) * 8;

    __shared__ __align__(16) __bf16 As0[BM * 32];
    __shared__ __align__(16) __bf16 As1[BM * 32];
    __shared__ __align__(16) __bf16 As2[BM * 32];
    __shared__ __align__(16) __bf16 Bs0[128 * 32];
    __shared__ __align__(16) __bf16 Bs1[128 * 32];
    __shared__ __align__(16) __bf16 Bs2[128 * 32];

    f32x4 acc[BM / 32][4] = {};

    const int sr = tid >> 2;
    const int sc = (((tid & 3) ^ ((tid >> 3) & 3)) << 3);

    const __bf16* pa0 = A + (size_t)(bm * BM + sr) * K + sc;
    const __bf16* pa1 = pa0 + (size_t)(BM == 128 ? 64 : 0) * K;
    const __bf16* pb0 = B + (size_t)(bn * 128 + sr) * K + sc;
    const __bf16* pb1 = pb0 + (size_t)64 * K;

    const int nt = K >> 5;

    gload_lds16(pa0, &As0[tid * 8]);
    if constexpr (BM == 128) gload_lds16(pa1, &As0[2048 + tid * 8]);
    gload_lds16(pb0, &Bs0[tid * 8]);
    gload_lds16(pb1, &Bs0[2048 + tid * 8]);
    if (nt > 1) {
        gload_lds16(pa0 + 32, &As1[tid * 8]);
        if constexpr (BM == 128) gload_lds16(pa1 + 32, &As1[2048 + tid * 8]);
        gload_lds16(pb0 + 32, &Bs1[tid * 8]);
        gload_lds16(pb1 + 32, &Bs1[2048 + tid * 8]);
    }

    int t = 0;
    for (; t + 2 < nt; t += 3) {
        KBODY(As0, Bs0, As2, Bs2, t + 2);
        KBODY(As1, Bs1, As0, Bs0, t + 3);
        KBODY(As2, Bs2, As1, Bs1, t + 4);
    }
    if (t < nt) {
        asm volatile("s_waitcnt vmcnt(0)" ::: "memory");
        __builtin_amdgcn_s_barrier();
        __builtin_amdgcn_sched_barrier(0);
        READMM(As0, Bs0);
        t++;
        if (t < nt) { READMM(As1, Bs1); }
    }

    const int row0 = bm * BM + wm * (BM / 2);
    const int col0 = bn * 128 + wn * 64;
#pragma unroll
    for (int i = 0; i < BM / 32; i++) {
#pragma unroll
        for (int j = 0; j < 4; j++) {
            const int col = col0 + j * 16 + lm;
#pragma unroll
            for (int r = 0; r < 4; r++) {
                const int row = row0 + i * 16 + lq * 4 + r;
                float v = acc[i][j][r];
                if (EP == EP_QKV) {
                    float vv = (col < 2048) ? ((v > 0.0f) ? (v + 1.0f) : expf(v)) : v;
                    __bf16* dst = (col < 1024) ? (__bf16*)C
                                : (col < 2048) ? (__bf16*)const_cast<__bf16*>(bias)
                                               : (__bf16*)const_cast<float*>(resid);
                    dst[(size_t)row * 1024 + (col & 1023)] = (__bf16)vv;
                } else {
                    if (EP == EP_ELU1) {
                        v = (v > 0.0f) ? (v + 1.0f) : expf(v);
                    } else if (EP == EP_BIAS_GELU) {
                        v += (float)bias[col];
                        v = 0.5f * v * (1.0f + erf_fast(v * 0.70710678118654752f));
                    } else if (EP == EP_BIAS_RES) {
                        v += (float)bias[col];
                        v += resid[(size_t)row * N + col];
                    }
                    C[(size_t)row * N + col] = (OutT)v;
                }
            }
        }
    }
}

// ---------------------------------------------------------------------------
// KV partials: block (nh, sc) computes KV[d,v] over 256 s-rows, plus Ksum.
// Non-atomic per-chunk partials + separate 1024-block reduce (round-8 proven;
// round-9 atomicAdd = 10x slower, round-15 fused split-K tail = 10x slower).
__global__ __launch_bounds__(256) void kv_kernel(const __bf16* __restrict__ Kf,
                                                 const __bf16* __restrict__ Vf,
                                                 float* __restrict__ pkv,
                                                 float* __restrict__ pks) {
    const int nh = blockIdx.x, sc = blockIdx.y;
    const int n = nh >> 3, h = nh & 7;
    const int tid = threadIdx.x;
    const int tv = tid & 15, td = tid >> 4;
    __shared__ __align__(16) __bf16 Kt[32 * 128];
    __shared__ __align__(16) __bf16 Vt[32 * 128];
    float acc[8][8] = {};
    float ks[8] = {};
    const size_t rowbase = (size_t)n * 4096 + (size_t)sc * 256;
    for (int s0 = 0; s0 < 256; s0 += 32) {
#pragma unroll
        for (int rep = 0; rep < 2; rep++) {
            const int s = tid + rep * 256;
            const int r = s >> 4, cs = (s & 15) * 8;
            const size_t gidx = (rowbase + s0 + r) * 1024 + h * 128 + cs;
            *(bf16x8*)&Kt[r * 128 + cs] = *(const bf16x8*)&Kf[gidx];
            *(bf16x8*)&Vt[r * 128 + cs] = *(const bf16x8*)&Vf[gidx];
        }
        __syncthreads();
#pragma unroll 4
        for (int s = 0; s < 32; s++) {
            const bf16x8 k8 = *(const bf16x8*)&Kt[s * 128 + td * 8];
            const bf16x8 v8 = *(const bf16x8*)&Vt[s * 128 + tv * 8];
            float kk[8], vv[8];
#pragma unroll
            for (int i = 0; i < 8; i++) { kk[i] = (float)k8[i]; vv[i] = (float)v8[i]; }
#pragma unroll
            for (int i = 0; i < 8; i++) {
                ks[i] += kk[i];
#pragma unroll
                for (int j = 0; j < 8; j++) acc[i][j] += kk[i] * vv[j];
            }
        }
        __syncthreads();
    }
    float* dst = pkv + ((size_t)sc * 16 + nh) * 16384;
#pragma unroll
    for (int i = 0; i < 8; i++)
#pragma unroll
        for (int j = 0; j < 8; j++)
            dst[(td * 8 + i) * 128 + tv * 8 + j] = acc[i][j];
    if (tv == 0) {
        float* ds2 = pks + ((size_t)sc * 16 + nh) * 128;
#pragma unroll
        for (int i = 0; i < 8; i++) ds2[td * 8 + i] = ks[i];
    }
}

__global__ __launch_bounds__(256) void kv_reduce(const float* __restrict__ pkv,
                                                 const float* __restrict__ pks,
                                                 __bf16* __restrict__ kvb,
                                                 float* __restrict__ ksf) {
    const int idx = blockIdx.x * 256 + threadIdx.x;
    float s = 0.0f;
#pragma unroll
    for (int c = 0; c < 16; c++) s += pkv[(size_t)c * 262144 + idx];
    kvb[idx] = (__bf16)s;
    if (idx < 2048) {
        float t = 0.0f;
#pragma unroll
        for (int c = 0; c < 16; c++) t += pks[c * 2048 + idx];
        ksf[idx] = t;
    }
}

// attn out + residual, z fused: s_row = sum_d q*ks[d] inline (sequential
// d-order == old z_kernel -> bit-identical z). x dtype templated.
template <typename XT>
__global__ __launch_bounds__(256, 2) void attn_out_kernel(
    const XT* __restrict__ x, const __bf16* __restrict__ Qf,
    const __bf16* __restrict__ kvb, const float* __restrict__ ksf,
    float* __restrict__ xmid) {
    const int nh = blockIdx.x, lc = blockIdx.y;
    const int n = nh >> 3, h = nh & 7;
    const int tid = threadIdx.x;
    __shared__ __align__(16) __bf16 KVs[128 * 128];
    __shared__ __align__(16) __bf16 Qs[64 * 128];
    __shared__ float Ks[128];
    const __bf16* kv = kvb + (size_t)nh * 16384;
    for (int i = tid * 8; i < 16384; i += 2048)
        *(bf16x8*)&KVs[i] = *(const bf16x8*)&kv[i];
    const size_t gr0 = (size_t)n * 4096 + (size_t)lc * 64;
#pragma unroll
    for (int rep = 0; rep < 4; rep++) {
        const int s = tid + rep * 256;
        const int r = s >> 4, cs = (s & 15) * 8;
        *(bf16x8*)&Qs[r * 128 + cs] = *(const bf16x8*)&Qf[(gr0 + r) * 1024 + h * 128 + cs];
    }
    if (tid < 128) Ks[tid] = ksf[(size_t)nh * 128 + tid];
    __syncthreads();
    const int tv = (tid & 15) * 8;
    const int tr0 = (tid >> 4) * 4;
    float acc[4][8] = {};
    float zs[4] = {};
    for (int d = 0; d < 128; d++) {
        const bf16x8 kv8 = *(const bf16x8*)&KVs[d * 128 + tv];
        const float ksd = Ks[d];
        float kf[8];
#pragma unroll
        for (int j = 0; j < 8; j++) kf[j] = (float)kv8[j];
#pragma unroll
        for (int rr = 0; rr < 4; rr++) {
            const float q = (float)Qs[(tr0 + rr) * 128 + d];
            zs[rr] += q * ksd;
#pragma unroll
            for (int j = 0; j < 8; j++) acc[rr][j] += q * kf[j];
        }
    }
#pragma unroll
    for (int rr = 0; rr < 4; rr++) {
        const size_t gi = (gr0 + tr0 + rr) * 1024 + h * 128 + tv;
        const float z = 1.0f / (zs[rr] + 1e-6f);
        const XT* xr = x + gi;
#pragma unroll
        for (int j = 0; j < 8; j++) xmid[gi + j] = (float)xr[j] + acc[rr][j] * z;
    }
}

// ---------------------------------------------------------------------------
extern "C" void kernel_launch(void* const* d_in, const int* in_sizes, int n_in,
                              void* d_out, int out_size, void* d_ws, size_t ws_size,
                              hipStream_t stream) {
    float* out = (float*)d_out;   // output is FP32 (reference output dtype)
    char* ws = (char*)d_ws;

    const int nx = 8388608, nw = 1048576, nw1 = 4194304, nb1 = 4096, ng = 1024;
    size_t off = 0;
    __bf16* cx   = (__bf16*)(ws + off); off += (size_t)nx * 2;
    __bf16* cwq  = (__bf16*)(ws + off); off += (size_t)nw * 2;   // cwq/cwk/cwv
    __bf16* cwk  = (__bf16*)(ws + off); off += (size_t)nw * 2;   // contiguous =
    __bf16* cwv  = (__bf16*)(ws + off); off += (size_t)nw * 2;   // B[3072,1024]
    __bf16* cw1  = (__bf16*)(ws + off); off += (size_t)nw1 * 2;
    __bf16* cb1  = (__bf16*)(ws + off); off += (size_t)nb1 * 2;
    __bf16* cw2  = (__bf16*)(ws + off); off += (size_t)nw1 * 2;
    __bf16* cb2  = (__bf16*)(ws + off); off += (size_t)ng * 2;
    __bf16* cg1  = (__bf16*)(ws + off); off += (size_t)ng * 2;
    __bf16* cbe1 = (__bf16*)(ws + off); off += (size_t)ng * 2;
    __bf16* cg2  = (__bf16*)(ws + off); off += (size_t)ng * 2;
    __bf16* cbe2 = (__bf16*)(ws + off); off += (size_t)ng * 2;
    int* flags = (int*)(ws + off); off += 64;

    char* PB = ws + off;
    __bf16* x2   = (__bf16*)(PB);                 // LN1 out; later LN2 out
    float*  pkv  = (float*)(PB + 33554432);
    __bf16* Qf   = (__bf16*)(PB + 16777216);
    __bf16* hbuf = (__bf16*)(PB + 16777216);      // MLP h chunk (over Qf+pkv)
    __bf16* Kf   = (__bf16*)(PB + 50331648);
    __bf16* Vf   = (__bf16*)(PB + 67108864);
    float*  xmid = (float*)(PB + 50331648);       // fp32 (over Kf/Vf)
    float*  pks  = (float*)(PB + 83886080);
    float*  ksf  = (float*)(PB + 84017152);
    __bf16* kvb  = (__bf16*)(PB + 84287488);      // ends PB+84,811,776
    __bf16* hbig = (__bf16*)(PB + 84811776);      // 64MB full-M hbuf (optional)
    const size_t need_single = (size_t)(PB - ws) + 84811776 + (size_t)8192 * 4096 * 2;
    const bool single_mlp = ws_size >= need_single;

    // 0+1. canonicalize weights + LN1 (merged when fp32 inputs).
    const bool is_f32 = (in_sizes[0] == nx * 4);
    if (is_f32) {
        CvtLn1 P;
        const float* srcs[11] = {(const float*)d_in[1], (const float*)d_in[2],
                                 (const float*)d_in[3], (const float*)d_in[4],
                                 (const float*)d_in[5], (const float*)d_in[6],
                                 (const float*)d_in[7], (const float*)d_in[8],
                                 (const float*)d_in[9], (const float*)d_in[10],
                                 (const float*)d_in[11]};
        __bf16* dsts[11] = {cwq, cwk, cwv, cw1, cb1, cw2, cb2, cg1, cbe1, cg2, cbe2};
        int ns[11] = {nw, nw, nw, nw1, nb1, nw1, ng, ng, ng, ng, ng};
        int b = 0;
        for (int k = 0; k < 11; k++) {
            P.J.s[k] = srcs[k]; P.J.d[k] = dsts[k]; P.J.n[k] = ns[k]; P.J.b0[k] = b;
            b += (ns[k] + 2047) / 2048;
        }
        P.x = (const float*)d_in[0];
        P.g = (const float*)d_in[8];
        P.b = (const float*)d_in[9];
        P.out = x2;
        P.bcvt = b;
        cvt_ln1_kernel<<<b + 8192, 256, 0, stream>>>(P);
    } else {
        sniff_kernel<<<1, 256, 0, stream>>>((const unsigned short*)d_in[0], flags);
        convert_kernel<<<nx / 2048, 256, 0, stream>>>(d_in[0], cx, nx, flags);
        convert_kernel<<<nw / 2048, 256, 0, stream>>>(d_in[1], cwq, nw, flags);
        convert_kernel<<<nw / 2048, 256, 0, stream>>>(d_in[2], cwk, nw, flags);
        convert_kernel<<<nw / 2048, 256, 0, stream>>>(d_in[3], cwv, nw, flags);
        convert_kernel<<<nw1 / 2048, 256, 0, stream>>>(d_in[4], cw1, nw1, flags);
        convert_kernel<<<2, 256, 0, stream>>>(d_in[5], cb1, nb1, flags);
        convert_kernel<<<nw1 / 2048, 256, 0, stream>>>(d_in[6], cw2, nw1, flags);
        convert_kernel<<<1, 256, 0, stream>>>(d_in[7], cb2, ng, flags);
        convert_kernel<<<1, 256, 0, stream>>>(d_in[8], cg1, ng, flags);
        convert_kernel<<<1, 256, 0, stream>>>(d_in[9], cbe1, ng, flags);
        convert_kernel<<<1, 256, 0, stream>>>(d_in[10], cg2, ng, flags);
        convert_kernel<<<1, 256, 0, stream>>>(d_in[11], cbe2, ng, flags);
        ln_kernel<__bf16><<<8192, 256, 0, stream>>>(cx, cg1, cbe1, x2);
    }

    // 2. fused QKV projection: B = [wq;wk;wv] contiguous, N=3072 (r5 proven)
    gemm_bt<EP_QKV, 128, __bf16><<<dim3(3072 / 128, 8192 / 128), 256, 0, stream>>>(
        x2, cwq, (const __bf16*)Kf, (const float*)Vf, Qf, 8192, 3072, 1024);

    // 3. KV + Ksum (non-atomic partials + 1024-block reduce)
    kv_kernel<<<dim3(16, 16), 256, 0, stream>>>(Kf, Vf, pkv, pks);
    kv_reduce<<<1024, 256, 0, stream>>>(pkv, pks, kvb, ksf);

    // 4. attention out (z fused) + residual -> xmid fp32 (over dead Kf/Vf)
    if (is_f32)
        attn_out_kernel<float><<<dim3(16, 64), 256, 0, stream>>>(
            (const float*)d_in[0], Qf, kvb, ksf, xmid);
    else
        attn_out_kernel<__bf16><<<dim3(16, 64), 256, 0, stream>>>(
            cx, Qf, kvb, ksf, xmid);

    // 5. LN2 + MLP; final epilogue writes FP32 out. Single-shot over M=8192
    //    when workspace allows; MLP2 BM=128 (grid (8,64)=512 blocks=2/CU).
    ln_kernel<float><<<8192, 256, 0, stream>>>(xmid, cg2, cbe2, x2);
    if (single_mlp) {
        gemm_bt<EP_BIAS_GELU, 128, __bf16><<<dim3(4096 / 128, 8192 / 128), 256, 0, stream>>>(
            x2, cw1, cb1, nullptr, hbig, 8192, 4096, 1024);
        gemm_bt<EP_BIAS_RES, 128, float><<<dim3(1024 / 128, 8192 / 128), 256, 0, stream>>>(
            hbig, cw2, cb2, xmid, out, 8192, 1024, 4096);
    } else {
        for (int c = 0; c < 2; c++) {
            const size_t ro = (size_t)c * 4096;
            gemm_bt<EP_BIAS_GELU, 128, __bf16><<<dim3(4096 / 128, 4096 / 128), 256, 0, stream>>>(
                x2 + ro * 1024, cw1, cb1, nullptr, hbuf, 4096, 4096, 1024);
            gemm_bt<EP_BIAS_RES, 64, float><<<dim3(1024 / 128, 4096 / 64), 256, 0, stream>>>(
                hbuf, cw2, cb2, xmid + ro * 1024, out + ro * 1024, 4096, 1024, 4096);
        }
    }
}